// Round 7
// baseline (243.369 us; speedup 1.0000x reference)
//
#include <hip/hip_runtime.h>
#include <hip/hip_bf16.h>

#define CCH 256      // channels
#define HH 128
#define WW 128
#define SS (HH*WW)   // 16384 pixels per batch
#define NB 8         // batch
#define NK 19        // keypoints
#define PTILE 16     // pixels per (1-wave) block
#define NTIL (NB * (SS / PTILE))   // 8192 tiles

typedef __attribute__((ext_vector_type(8))) short short8v;   // 8 bf16 = 4 VGPR (MFMA operand)
typedef __attribute__((ext_vector_type(4))) float f32x4;     // MFMA accum

static __device__ __forceinline__ unsigned short f2bf(float x) {
    __hip_bfloat16 h = __float2bfloat16(x);
    return *reinterpret_cast<unsigned short*>(&h);
}
static __device__ __forceinline__ float bf2f(unsigned short u) {
    union { unsigned int i; float f; } z; z.i = ((unsigned int)u) << 16; return z.f;
}
static __device__ __forceinline__ float tanh_fast(float x) {
    // 1 - 2/(e^{2x}+1), with v_rcp instead of exact div (tolerance is generous)
    float e = __expf(2.f * x);
    return 1.f - 2.f * __builtin_amdgcn_rcpf(e + 1.f);
}
static __device__ __forceinline__ float sigmoid_fast(float z) {
    return __builtin_amdgcn_rcpf(1.f + __expf(-z));
}

// ---------------------------------------------------------------------------
// Kernel 1: precompute folded biases, delta weights, keypoint pixels, the
// fused {cb, aw} table, and img_fc_w in MFMA A-fragment order:
//   Wfrag[((ks*16 + m)*64 + lane)*8 + j] = bf16(W[m*16 + (lane&15)][ks*32 + (lane>>4)*8 + j])
// ---------------------------------------------------------------------------
__global__ __launch_bounds__(256) void precompute_kernel(
    const float* __restrict__ kf,        // [B,K,3]
    const float* __restrict__ img_fc_w,  // [256,256]
    const float* __restrict__ img_fc_b,  // [256]
    const float* __restrict__ kp_proj_w, // [19,19]
    const float* __restrict__ kp_proj_b, // [19]
    const float* __restrict__ kp_fc_w,   // [256,19]
    const float* __restrict__ kp_fc_b,   // [256]
    const float* __restrict__ attn_fc_w, // [256]
    float* __restrict__ cb,              // [256] combined bias
    float* __restrict__ delta,           // [256*19]
    int* __restrict__ pix,               // [B*K]
    unsigned short* __restrict__ Wfrag,  // [8*16*64*8]
    float2* __restrict__ cw2)            // [256] {cb, aw}
{
    int t = threadIdx.x;
    {
        float acc = img_fc_b[t] + kp_fc_b[t];
        for (int k2 = 0; k2 < NK; ++k2) acc += kp_fc_w[t * NK + k2] * kp_proj_b[k2];
        cb[t] = acc;
        cw2[t] = make_float2(acc, attn_fc_w[t]);
        for (int k = 0; k < NK; ++k) {
            float d = 0.f;
            for (int k2 = 0; k2 < NK; ++k2) d += kp_fc_w[t * NK + k2] * kp_proj_w[k2 * NK + k];
            delta[t * NK + k] = d;
        }
    }
    if (t < NB * NK) {
        float kx = kf[t * 3 + 0], ky = kf[t * 3 + 1], vis = kf[t * 3 + 2];
        int p = -1;
        if (vis > 0.f) {
            int xi = (int)fminf(fmaxf(kx * (1.f / (float)WW), 0.f), (float)(WW - 1));
            int yi = (int)fminf(fmaxf(ky * (1.f / (float)HH), 0.f), (float)(HH - 1));
            p = yi * WW + xi;
        }
        pix[t] = p;
    }
    for (int g = t; g < 8 * 16 * 64; g += 256) {
        int lane = g & 63;
        int m = (g >> 6) & 15;
        int ks = g >> 10;
        int o = m * 16 + (lane & 15);
        int c0 = ks * 32 + (lane >> 4) * 8;
#pragma unroll
        for (int j = 0; j < 8; ++j)
            Wfrag[g * 8 + j] = f2bf(img_fc_w[o * CCH + c0 + j]);
    }
}

// ---------------------------------------------------------------------------
// Kernel 2: barrier-free main kernel. One 64-lane wave per block; each wave
// owns 16 pixels x all 256 outputs. X (B-operand) lives in 32 VGPRs; acc in
// 64 VGPRs; o-reduction fully in-wave via shfl_xor. LDS only holds the 2KB
// {cb,aw} broadcast table (one trivial 1-wave sync before any X load).
// A (Wfrag) is re-read from L2 per tile (128KB, L2-resident).
// ---------------------------------------------------------------------------
__global__ __launch_bounds__(64, 4) void main_kernel(
    const float* __restrict__ img,        // [B,256,16384]
    const unsigned short* __restrict__ Wfrag,
    const float2* __restrict__ cw2,       // [256] {cb, aw}
    const float* __restrict__ attn_b,     // [1]
    float* __restrict__ out)              // [B,256,16384]
{
    __shared__ float2 cwl[256];           // 2KB broadcast table

    const int l = threadIdx.x;
    // XCD-chunked bijective swizzle: 8192 tiles = 8 XCDs x 1024; consecutive
    // tiles (sharing 256B DRAM granules) stay on one XCD.
    const int bid = blockIdx.x;
    const int swz = (bid & 7) * (NTIL / 8) + (bid >> 3);
    const int b = swz >> 10;                  // batch
    const int px0 = (swz & 1023) * PTILE;     // pixel base
    const float* imgb = img + (size_t)b * CCH * SS;
    float* outb = out + (size_t)b * CCH * SS;

    const int sg = px0 + (l & 15);            // this lane's pixel
    const int cg8 = (l >> 4) * 8;             // this lane's channel octet base

    // ---- stage {cb,aw} to LDS (before X loads so the sync doesn't drain them)
    {
        const float4* src = reinterpret_cast<const float4*>(cw2);
        float4* dst = reinterpret_cast<float4*>(cwl);
        dst[l] = src[l];
        dst[l + 64] = src[l + 64];
    }
    __syncthreads();   // single-wave: cheap; orders ds_writes before epilogue reads

    // ---- X loads: 64 independent scalar dwords, all in flight -------------
    float xf[8][8];
#pragma unroll
    for (int ks = 0; ks < 8; ++ks)
#pragma unroll
        for (int j = 0; j < 8; ++j)
            xf[ks][j] = imgb[(size_t)(ks * 32 + cg8 + j) * SS + sg];

    // ---- pack to MFMA B-fragments (k = (l>>4)*8 + j within each K=32 step)
    short8v bfr[8];
#pragma unroll
    for (int ks = 0; ks < 8; ++ks) {
        short8v pk;
#pragma unroll
        for (int j = 0; j < 8; ++j) pk[j] = (short)f2bf(xf[ks][j]);
        bfr[ks] = pk;
    }

    // ---- K loop: 128 MFMA, A streamed from L2-resident Wfrag --------------
    f32x4 acc[16];
#pragma unroll
    for (int m = 0; m < 16; ++m) acc[m] = (f32x4){0.f, 0.f, 0.f, 0.f};

#pragma unroll
    for (int ks = 0; ks < 8; ++ks) {
#pragma unroll
        for (int m = 0; m < 16; ++m) {
            short8v a = *reinterpret_cast<const short8v*>(
                &Wfrag[(((ks * 16 + m) * 64) + l) * 8]);
            acc[m] = __builtin_amdgcn_mfma_f32_16x16x32_bf16(a, bfr[ks], acc[m], 0, 0, 0);
        }
    }

    // ---- epilogue, fully in-wave ------------------------------------------
    // D layout: s = l&15, o = m*16 + (l>>4)*4 + r
    float z = 0.f;
#pragma unroll
    for (int m = 0; m < 16; ++m) {
        int o4 = m * 16 + ((l >> 4) << 2);
        float4 q0 = *reinterpret_cast<const float4*>(&cwl[o4]);      // {cb,aw}[r=0,1]
        float4 q1 = *reinterpret_cast<const float4*>(&cwl[o4 + 2]);  // {cb,aw}[r=2,3]
        z += q0.y * tanh_fast(acc[m][0] + q0.x);
        z += q0.w * tanh_fast(acc[m][1] + q0.z);
        z += q1.y * tanh_fast(acc[m][2] + q1.x);
        z += q1.w * tanh_fast(acc[m][3] + q1.z);
    }
    z += __shfl_xor(z, 16);
    z += __shfl_xor(z, 32);
    float sc = sigmoid_fast(z + attn_b[0]);

    // ---- stores: same addressing as loads, scaled bf16 values -------------
#pragma unroll
    for (int ks = 0; ks < 8; ++ks)
#pragma unroll
        for (int j = 0; j < 8; ++j)
            outb[(size_t)(ks * 32 + cg8 + j) * SS + sg] =
                bf2f((unsigned short)bfr[ks][j]) * sc;
}

// ---------------------------------------------------------------------------
// Kernel 3: exact fp32 fixup for keypoint pixels (<=152). One block per (b,k).
// ---------------------------------------------------------------------------
__global__ __launch_bounds__(256) void fixup_kernel(
    const float* __restrict__ img,
    const float* __restrict__ img_fc_w,
    const float* __restrict__ aw,
    const float* __restrict__ attn_b,
    const float* __restrict__ cb,
    const float* __restrict__ delta,
    const int* __restrict__ pix,
    float* __restrict__ out)
{
    int bk = blockIdx.x;            // 0..151
    int b = bk / NK;
    int p = pix[bk];
    if (p < 0) return;              // uniform branch, before any barrier
    __shared__ float x[256];
    __shared__ float red[256];
    __shared__ float ssc;
    int t = threadIdx.x;
    const float* imgb = img + (size_t)b * CCH * SS;
    x[t] = imgb[(size_t)t * SS + p];
    __syncthreads();
    float dsum = 0.f;
    for (int k2 = 0; k2 < NK; ++k2)
        if (pix[b * NK + k2] == p) dsum += delta[t * NK + k2];
    float acc = cb[t] + dsum;
    for (int c = 0; c < CCH; ++c) acc += img_fc_w[t * CCH + c] * x[c];
    red[t] = aw[t] * tanh_fast(acc);
    __syncthreads();
    for (int off = 128; off > 0; off >>= 1) {
        if (t < off) red[t] += red[t + off];
        __syncthreads();
    }
    if (t == 0) ssc = sigmoid_fast(red[0] + attn_b[0]);
    __syncthreads();
    out[(size_t)(b * CCH + t) * SS + p] = x[t] * ssc;
}

// ---------------------------------------------------------------------------
extern "C" void kernel_launch(void* const* d_in, const int* in_sizes, int n_in,
                              void* d_out, int out_size, void* d_ws, size_t ws_size,
                              hipStream_t stream) {
    (void)in_sizes; (void)n_in; (void)out_size; (void)ws_size;
    const float* img       = (const float*)d_in[0];
    const float* kf        = (const float*)d_in[1];
    const float* img_fc_w  = (const float*)d_in[2];
    const float* img_fc_b  = (const float*)d_in[3];
    const float* kp_proj_w = (const float*)d_in[4];
    const float* kp_proj_b = (const float*)d_in[5];
    const float* kp_fc_w   = (const float*)d_in[6];
    const float* kp_fc_b   = (const float*)d_in[7];
    const float* attn_fc_w = (const float*)d_in[8];
    const float* attn_fc_b = (const float*)d_in[9];
    float* out = (float*)d_out;

    char* ws = (char*)d_ws;
    float* cb             = (float*)(ws);             // 256 f  ->   1024 B
    float* delta          = (float*)(ws + 1024);      // 4864 f -> 19456 B
    int*   pix            = (int*)  (ws + 20480);     // 152 i  ->   608 B
    unsigned short* Wfrag = (unsigned short*)(ws + 21504);  // 131072 B
    float2* cw2           = (float2*)(ws + 152576);   // 256 float2 -> 2048 B

    precompute_kernel<<<1, 256, 0, stream>>>(kf, img_fc_w, img_fc_b, kp_proj_w,
                                             kp_proj_b, kp_fc_w, kp_fc_b, attn_fc_w,
                                             cb, delta, pix, Wfrag, cw2);
    main_kernel<<<NTIL, 64, 0, stream>>>(img, Wfrag, cw2, attn_fc_b, out);
    fixup_kernel<<<NB * NK, 256, 0, stream>>>(img, img_fc_w, attn_fc_w, attn_fc_b,
                                              cb, delta, pix, out);
}

// Round 8
// 83.714 us; speedup vs baseline: 2.9072x; 2.9072x over previous
//
#include <hip/hip_runtime.h>
#include <hip/hip_bf16.h>

#define CCH 256      // channels
#define HH 128
#define WW 128
#define SS (HH*WW)   // 16384 pixels per batch
#define NB 8         // batch
#define NK 19        // keypoints
#define STILE 32     // pixels per block
#define NTIL (NB * (SS / STILE))   // 4096 tiles

typedef __attribute__((ext_vector_type(8))) short short8v;   // 8 bf16 = 4 VGPR (MFMA operand)
typedef __attribute__((ext_vector_type(4))) float f32x4;     // MFMA accum

static __device__ __forceinline__ unsigned short f2bf(float x) {
    __hip_bfloat16 h = __float2bfloat16(x);
    return *reinterpret_cast<unsigned short*>(&h);
}
static __device__ __forceinline__ float bf2f(unsigned short u) {
    union { unsigned int i; float f; } z; z.i = ((unsigned int)u) << 16; return z.f;
}
static __device__ __forceinline__ float tanh_fast(float x) {
    // 1 - 2/(e^{2x}+1) with v_rcp (tolerance is generous; verified 0.0156)
    float e = __expf(2.f * x);
    return 1.f - 2.f * __builtin_amdgcn_rcpf(e + 1.f);
}
static __device__ __forceinline__ float sigmoid_fast(float z) {
    return __builtin_amdgcn_rcpf(1.f + __expf(-z));
}

// ---------------------------------------------------------------------------
// Kernel 1: precompute folded biases, delta weights, keypoint pixels, and
// img_fc_w rearranged to bf16 in MFMA A-fragment order:
//   Wfrag[((ks*16 + ot)*64 + lane)*8 + j] = bf16(W[ot*16 + (lane&15)][ks*32 + (lane>>4)*8 + j])
// ---------------------------------------------------------------------------
__global__ __launch_bounds__(256) void precompute_kernel(
    const float* __restrict__ kf,        // [B,K,3]
    const float* __restrict__ img_fc_w,  // [256,256]
    const float* __restrict__ img_fc_b,  // [256]
    const float* __restrict__ kp_proj_w, // [19,19]
    const float* __restrict__ kp_proj_b, // [19]
    const float* __restrict__ kp_fc_w,   // [256,19]
    const float* __restrict__ kp_fc_b,   // [256]
    float* __restrict__ cb,              // [256] combined bias
    float* __restrict__ delta,           // [256*19]
    int* __restrict__ pix,               // [B*K]
    unsigned short* __restrict__ Wfrag)  // [8*16*64*8]
{
    int t = threadIdx.x;
    {
        float acc = img_fc_b[t] + kp_fc_b[t];
        for (int k2 = 0; k2 < NK; ++k2) acc += kp_fc_w[t * NK + k2] * kp_proj_b[k2];
        cb[t] = acc;
        for (int k = 0; k < NK; ++k) {
            float d = 0.f;
            for (int k2 = 0; k2 < NK; ++k2) d += kp_fc_w[t * NK + k2] * kp_proj_w[k2 * NK + k];
            delta[t * NK + k] = d;
        }
    }
    if (t < NB * NK) {
        float kx = kf[t * 3 + 0], ky = kf[t * 3 + 1], vis = kf[t * 3 + 2];
        int p = -1;
        if (vis > 0.f) {
            int xi = (int)fminf(fmaxf(kx * (1.f / (float)WW), 0.f), (float)(WW - 1));
            int yi = (int)fminf(fmaxf(ky * (1.f / (float)HH), 0.f), (float)(HH - 1));
            p = yi * WW + xi;
        }
        pix[t] = p;
    }
    for (int g = t; g < 8 * 16 * 64; g += 256) {
        int lane = g & 63;
        int ot = (g >> 6) & 15;
        int ks = g >> 10;
        int o = ot * 16 + (lane & 15);
        int c0 = ks * 32 + (lane >> 4) * 8;
#pragma unroll
        for (int j = 0; j < 8; ++j)
            Wfrag[g * 8 + j] = f2bf(img_fc_w[o * CCH + c0 + j]);
    }
}

// ---------------------------------------------------------------------------
// Kernel 2: main fused GEMM + epilogue. 4096 blocks x 512 thr (8 waves).
// Tile: 256 o x 32 px. Wave w owns o in [w*32, w*32+32) (m=2), n=2 s-frags.
// Small per-block state (acc 16 AGPR, staging 16 VGPR transient) -> target
// 8 waves/SIMD, 4 blocks/CU resident, staggered load phases.
// Thread owns 8 channels (c0 = (t>>4)*8) x 2 pixels (pq = (t&15)*2).
// ---------------------------------------------------------------------------
__global__ __launch_bounds__(512, 4) void main_kernel(
    const float* __restrict__ img,        // [B,256,16384]
    const unsigned short* __restrict__ Wfrag,
    const float* __restrict__ cb,         // [256]
    const float* __restrict__ aw,         // attn_fc_w [256]
    const float* __restrict__ attn_b,     // [1]
    float* __restrict__ out)              // [B,256,16384]
{
    __shared__ unsigned short Xl[STILE * 256];  // 16KB bf16 [s][c], 16B-block swizzled
    __shared__ float partial[8][STILE];
    __shared__ float scl[STILE];
    __shared__ float cbl[256];
    __shared__ float awl[256];

    const int t = threadIdx.x;
    const int l = t & 63;        // lane
    const int w = t >> 6;        // wave 0..7

    // XCD-chunked bijective swizzle (4096 % 8 == 0): XCD x covers a
    // contiguous range of tiles -> 128B row segments of adjacent tiles share
    // an XCD's L2 (no cross-XCD granule split).
    const int bid = blockIdx.x;
    const int swz = (bid & 7) * (NTIL / 8) + (bid >> 3);
    const int b = swz >> 9;                  // 512 tiles per batch
    const int sb = (swz & 511) * STILE;
    const float* imgb = img + (size_t)b * CCH * SS;

    if (t < 256) { cbl[t] = cb[t]; awl[t] = aw[t]; }

    const int pq = (t & 15) * 2;      // 2 pixels this thread owns
    const int cg = t >> 4;            // 0..31: channel octet (c0 = cg*8)
    const int c0 = cg * 8;

    // ---- phase 1: 8 float2 loads (all in flight), cvt, 2 ds_write_b128 ----
    {
        float2 xf2[8];
#pragma unroll
        for (int j = 0; j < 8; ++j)
            xf2[j] = *reinterpret_cast<const float2*>(imgb + (size_t)(c0 + j) * SS + sb + pq);
#pragma unroll
        for (int p = 0; p < 2; ++p) {
            int s = pq + p;
            short8v pk;
#pragma unroll
            for (int j = 0; j < 8; ++j)
                pk[j] = (short)f2bf(p ? xf2[j].y : xf2[j].x);
            int idx = s * 256 + ((cg ^ (s & 7)) << 3);
            *reinterpret_cast<short8v*>(&Xl[idx]) = pk;
        }
    }
    __syncthreads();

    // ---- phase 2: K loop, 8 steps of K=32, 4 MFMA per step per wave -------
    f32x4 acc[2][2];
#pragma unroll
    for (int m = 0; m < 2; ++m)
#pragma unroll
        for (int n = 0; n < 2; ++n)
            acc[m][n] = (f32x4){0.f, 0.f, 0.f, 0.f};

#pragma unroll
    for (int ks = 0; ks < 8; ++ks) {
        short8v a[2], bf[2];
#pragma unroll
        for (int m = 0; m < 2; ++m)
            a[m] = *reinterpret_cast<const short8v*>(
                &Wfrag[(((ks * 16 + (w * 2 + m)) * 64) + l) * 8]);
        const int cblk = ks * 4 + (l >> 4);
#pragma unroll
        for (int n = 0; n < 2; ++n) {
            int s = n * 16 + (l & 15);
            bf[n] = *reinterpret_cast<const short8v*>(
                &Xl[s * 256 + ((cblk ^ (s & 7)) << 3)]);
        }
#pragma unroll
        for (int m = 0; m < 2; ++m)
#pragma unroll
            for (int n = 0; n < 2; ++n)
                acc[m][n] = __builtin_amdgcn_mfma_f32_16x16x32_bf16(a[m], bf[n], acc[m][n], 0, 0, 0);
    }

    // ---- phase 3: score[s] = sigmoid(attn_b + sum_o aw[o]*tanh(T[o,s]+cb[o]))
    // D layout: s = n*16 + (l&15), o = (w*2+m)*16 + (l>>4)*4 + r
    float p2[2];
#pragma unroll
    for (int n = 0; n < 2; ++n) {
        float accp = 0.f;
#pragma unroll
        for (int m = 0; m < 2; ++m)
#pragma unroll
            for (int r = 0; r < 4; ++r) {
                int o = (w * 2 + m) * 16 + ((l >> 4) << 2) + r;
                accp += awl[o] * tanh_fast(acc[m][n][r] + cbl[o]);
            }
        accp += __shfl_xor(accp, 16);
        accp += __shfl_xor(accp, 32);
        p2[n] = accp;
    }
    if (l < 16) {
        partial[w][l] = p2[0];
        partial[w][16 + l] = p2[1];
    }
    __syncthreads();
    if (t < STILE) {
        float z = attn_b[0];
#pragma unroll
        for (int ww = 0; ww < 8; ++ww) z += partial[ww][t];
        scl[t] = sigmoid_fast(z);
    }
    __syncthreads();

    // ---- phase 4: LDS readback, scale, float2 stores (128B/16-lane group) --
    {
        float s0 = scl[pq], s1 = scl[pq + 1];
        short8v v0, v1;
        {
            int i0 = pq * 256 + ((cg ^ (pq & 7)) << 3);
            int i1 = (pq + 1) * 256 + ((cg ^ ((pq + 1) & 7)) << 3);
            v0 = *reinterpret_cast<const short8v*>(&Xl[i0]);
            v1 = *reinterpret_cast<const short8v*>(&Xl[i1]);
        }
#pragma unroll
        for (int j = 0; j < 8; ++j) {
            float2 o2;
            o2.x = bf2f((unsigned short)v0[j]) * s0;
            o2.y = bf2f((unsigned short)v1[j]) * s1;
            *reinterpret_cast<float2*>(
                out + (size_t)(b * CCH + c0 + j) * SS + sb + pq) = o2;
        }
    }
}

// ---------------------------------------------------------------------------
// Kernel 3: exact fp32 fixup for keypoint pixels (<=152). One block per (b,k).
// ---------------------------------------------------------------------------
__global__ __launch_bounds__(256) void fixup_kernel(
    const float* __restrict__ img,
    const float* __restrict__ img_fc_w,
    const float* __restrict__ aw,
    const float* __restrict__ attn_b,
    const float* __restrict__ cb,
    const float* __restrict__ delta,
    const int* __restrict__ pix,
    float* __restrict__ out)
{
    int bk = blockIdx.x;            // 0..151
    int b = bk / NK;
    int p = pix[bk];
    if (p < 0) return;              // uniform branch, before any barrier
    __shared__ float x[256];
    __shared__ float red[256];
    __shared__ float ssc;
    int t = threadIdx.x;
    const float* imgb = img + (size_t)b * CCH * SS;
    x[t] = imgb[(size_t)t * SS + p];
    __syncthreads();
    float dsum = 0.f;
    for (int k2 = 0; k2 < NK; ++k2)
        if (pix[b * NK + k2] == p) dsum += delta[t * NK + k2];
    float acc = cb[t] + dsum;
    for (int c = 0; c < CCH; ++c) acc += img_fc_w[t * CCH + c] * x[c];
    red[t] = aw[t] * tanh_fast(acc);
    __syncthreads();
    for (int off = 128; off > 0; off >>= 1) {
        if (t < off) red[t] += red[t + off];
        __syncthreads();
    }
    if (t == 0) ssc = sigmoid_fast(red[0] + attn_b[0]);
    __syncthreads();
    out[(size_t)(b * CCH + t) * SS + p] = x[t] * ssc;
}

// ---------------------------------------------------------------------------
extern "C" void kernel_launch(void* const* d_in, const int* in_sizes, int n_in,
                              void* d_out, int out_size, void* d_ws, size_t ws_size,
                              hipStream_t stream) {
    (void)in_sizes; (void)n_in; (void)out_size; (void)ws_size;
    const float* img       = (const float*)d_in[0];
    const float* kf        = (const float*)d_in[1];
    const float* img_fc_w  = (const float*)d_in[2];
    const float* img_fc_b  = (const float*)d_in[3];
    const float* kp_proj_w = (const float*)d_in[4];
    const float* kp_proj_b = (const float*)d_in[5];
    const float* kp_fc_w   = (const float*)d_in[6];
    const float* kp_fc_b   = (const float*)d_in[7];
    const float* attn_fc_w = (const float*)d_in[8];
    const float* attn_fc_b = (const float*)d_in[9];
    float* out = (float*)d_out;

    char* ws = (char*)d_ws;
    float* cb             = (float*)(ws);            // 256 f  ->   1024 B
    float* delta          = (float*)(ws + 1024);     // 4864 f -> 19456 B
    int*   pix            = (int*)  (ws + 20480);    // 152 i  ->   608 B
    unsigned short* Wfrag = (unsigned short*)(ws + 21504); // 131072 B

    precompute_kernel<<<1, 256, 0, stream>>>(kf, img_fc_w, img_fc_b, kp_proj_w,
                                             kp_proj_b, kp_fc_w, kp_fc_b,
                                             cb, delta, pix, Wfrag);
    main_kernel<<<NTIL, 512, 0, stream>>>(img, Wfrag, cb,
                                          attn_fc_w, attn_fc_b, out);
    fixup_kernel<<<NB * NK, 256, 0, stream>>>(img, img_fc_w, attn_fc_w, attn_fc_b,
                                              cb, delta, pix, out);
}

// Round 10
// 77.834 us; speedup vs baseline: 3.1268x; 1.0755x over previous
//
#include <hip/hip_runtime.h>
#include <hip/hip_bf16.h>

#define CCH 256      // channels
#define HH 128
#define WW 128
#define SS (HH*WW)   // 16384 pixels per batch
#define NB 8         // batch
#define NK 19        // keypoints
#define STILE 32     // pixels per block
#define NTIL (NB * (SS / STILE))   // 4096 tiles

typedef __attribute__((ext_vector_type(8))) short short8v;   // 8 bf16 = 4 VGPR (MFMA operand)
typedef __attribute__((ext_vector_type(4))) float f32x4;     // MFMA accum
typedef __attribute__((ext_vector_type(2))) float f32x2;     // native float2 (nt-store OK)

static __device__ __forceinline__ unsigned short f2bf(float x) {
    __hip_bfloat16 h = __float2bfloat16(x);
    return *reinterpret_cast<unsigned short*>(&h);
}
static __device__ __forceinline__ float bf2f(unsigned short u) {
    union { unsigned int i; float f; } z; z.i = ((unsigned int)u) << 16; return z.f;
}
static __device__ __forceinline__ float tanh_fast(float x) {
    // 1 - 2/(e^{2x}+1) with v_rcp (tolerance is generous; verified 0.0156)
    float e = __expf(2.f * x);
    return 1.f - 2.f * __builtin_amdgcn_rcpf(e + 1.f);
}
static __device__ __forceinline__ float sigmoid_fast(float z) {
    return __builtin_amdgcn_rcpf(1.f + __expf(-z));
}

// ---------------------------------------------------------------------------
// Kernel 1: precompute folded biases, delta weights, keypoint pixels, and
// img_fc_w rearranged to bf16 in MFMA A-fragment order:
//   Wfrag[((ks*16 + ot)*64 + lane)*8 + j] = bf16(W[ot*16 + (lane&15)][ks*32 + (lane>>4)*8 + j])
// ---------------------------------------------------------------------------
__global__ __launch_bounds__(256) void precompute_kernel(
    const float* __restrict__ kf,        // [B,K,3]
    const float* __restrict__ img_fc_w,  // [256,256]
    const float* __restrict__ img_fc_b,  // [256]
    const float* __restrict__ kp_proj_w, // [19,19]
    const float* __restrict__ kp_proj_b, // [19]
    const float* __restrict__ kp_fc_w,   // [256,19]
    const float* __restrict__ kp_fc_b,   // [256]
    float* __restrict__ cb,              // [256] combined bias
    float* __restrict__ delta,           // [256*19]
    int* __restrict__ pix,               // [B*K]
    unsigned short* __restrict__ Wfrag)  // [8*16*64*8]
{
    int t = threadIdx.x;
    {
        float acc = img_fc_b[t] + kp_fc_b[t];
        for (int k2 = 0; k2 < NK; ++k2) acc += kp_fc_w[t * NK + k2] * kp_proj_b[k2];
        cb[t] = acc;
        for (int k = 0; k < NK; ++k) {
            float d = 0.f;
            for (int k2 = 0; k2 < NK; ++k2) d += kp_fc_w[t * NK + k2] * kp_proj_w[k2 * NK + k];
            delta[t * NK + k] = d;
        }
    }
    if (t < NB * NK) {
        float kx = kf[t * 3 + 0], ky = kf[t * 3 + 1], vis = kf[t * 3 + 2];
        int p = -1;
        if (vis > 0.f) {
            int xi = (int)fminf(fmaxf(kx * (1.f / (float)WW), 0.f), (float)(WW - 1));
            int yi = (int)fminf(fmaxf(ky * (1.f / (float)HH), 0.f), (float)(HH - 1));
            p = yi * WW + xi;
        }
        pix[t] = p;
    }
    for (int g = t; g < 8 * 16 * 64; g += 256) {
        int lane = g & 63;
        int ot = (g >> 6) & 15;
        int ks = g >> 10;
        int o = ot * 16 + (lane & 15);
        int c0 = ks * 32 + (lane >> 4) * 8;
#pragma unroll
        for (int j = 0; j < 8; ++j)
            Wfrag[g * 8 + j] = f2bf(img_fc_w[o * CCH + c0 + j]);
    }
}

// ---------------------------------------------------------------------------
// Kernel 2: main fused GEMM + epilogue. 4096 blocks x 512 thr (8 waves).
// Tile: 256 o x 32 px. Wave w owns o in [w*32, w*32+32) (m=2), n=2 s-frags.
// Thread owns 8 channels (c0 = (t>>4)*8) x 2 pixels (pq = (t&15)*2).
// R9 changes vs R8: (1) output stores are NON-TEMPORAL (bypass L2/L3 alloc
// -> img stays L3-resident across replays, HBM sees a clean write stream);
// (2) final score reduction is computed redundantly per-thread (drops the
// t<32 serialization and the 3rd barrier).
// ---------------------------------------------------------------------------
__global__ __launch_bounds__(512, 4) void main_kernel(
    const float* __restrict__ img,        // [B,256,16384]
    const unsigned short* __restrict__ Wfrag,
    const float* __restrict__ cb,         // [256]
    const float* __restrict__ aw,         // attn_fc_w [256]
    const float* __restrict__ attn_b,     // [1]
    float* __restrict__ out)              // [B,256,16384]
{
    __shared__ unsigned short Xl[STILE * 256];  // 16KB bf16 [s][c], 16B-block swizzled
    __shared__ float partial[8][STILE];
    __shared__ float cbl[256];
    __shared__ float awl[256];

    const int t = threadIdx.x;
    const int l = t & 63;        // lane
    const int w = t >> 6;        // wave 0..7

    // XCD-chunked bijective swizzle (4096 % 8 == 0): each XCD covers a
    // contiguous range of tiles (no cross-XCD granule split).
    const int bid = blockIdx.x;
    const int swz = (bid & 7) * (NTIL / 8) + (bid >> 3);
    const int b = swz >> 9;                  // 512 tiles per batch
    const int sb = (swz & 511) * STILE;
    const float* imgb = img + (size_t)b * CCH * SS;

    if (t < 256) { cbl[t] = cb[t]; awl[t] = aw[t]; }

    const int pq = (t & 15) * 2;      // 2 pixels this thread owns
    const int cg = t >> 4;            // 0..31: channel octet (c0 = cg*8)
    const int c0 = cg * 8;

    // ---- phase 1: 8 float2 loads (all in flight), cvt, 2 ds_write_b128 ----
    {
        f32x2 xf2[8];
#pragma unroll
        for (int j = 0; j < 8; ++j)
            xf2[j] = *reinterpret_cast<const f32x2*>(imgb + (size_t)(c0 + j) * SS + sb + pq);
#pragma unroll
        for (int p = 0; p < 2; ++p) {
            int s = pq + p;
            short8v pk;
#pragma unroll
            for (int j = 0; j < 8; ++j)
                pk[j] = (short)f2bf(xf2[j][p]);
            int idx = s * 256 + ((cg ^ (s & 7)) << 3);
            *reinterpret_cast<short8v*>(&Xl[idx]) = pk;
        }
    }
    __syncthreads();

    // ---- phase 2: K loop, 8 steps of K=32, 4 MFMA per step per wave -------
    f32x4 acc[2][2];
#pragma unroll
    for (int m = 0; m < 2; ++m)
#pragma unroll
        for (int n = 0; n < 2; ++n)
            acc[m][n] = (f32x4){0.f, 0.f, 0.f, 0.f};

#pragma unroll
    for (int ks = 0; ks < 8; ++ks) {
        short8v a[2], bf[2];
#pragma unroll
        for (int m = 0; m < 2; ++m)
            a[m] = *reinterpret_cast<const short8v*>(
                &Wfrag[(((ks * 16 + (w * 2 + m)) * 64) + l) * 8]);
        const int cblk = ks * 4 + (l >> 4);
#pragma unroll
        for (int n = 0; n < 2; ++n) {
            int s = n * 16 + (l & 15);
            bf[n] = *reinterpret_cast<const short8v*>(
                &Xl[s * 256 + ((cblk ^ (s & 7)) << 3)]);
        }
#pragma unroll
        for (int m = 0; m < 2; ++m)
#pragma unroll
            for (int n = 0; n < 2; ++n)
                acc[m][n] = __builtin_amdgcn_mfma_f32_16x16x32_bf16(a[m], bf[n], acc[m][n], 0, 0, 0);
    }

    // ---- phase 3: score[s] = sigmoid(attn_b + sum_o aw[o]*tanh(T[o,s]+cb[o]))
    // D layout: s = n*16 + (l&15), o = (w*2+m)*16 + (l>>4)*4 + r
    float p2[2];
#pragma unroll
    for (int n = 0; n < 2; ++n) {
        float accp = 0.f;
#pragma unroll
        for (int m = 0; m < 2; ++m)
#pragma unroll
            for (int r = 0; r < 4; ++r) {
                int o = (w * 2 + m) * 16 + ((l >> 4) << 2) + r;
                accp += awl[o] * tanh_fast(acc[m][n][r] + cbl[o]);
            }
        accp += __shfl_xor(accp, 16);
        accp += __shfl_xor(accp, 32);
        p2[n] = accp;
    }
    if (l < 16) {
        partial[w][l] = p2[0];
        partial[w][16 + l] = p2[1];
    }
    __syncthreads();

    // ---- phase 4: per-thread redundant final reduce + nt stores -----------
    {
        const float ab = attn_b[0];
        float z0 = ab, z1 = ab;
#pragma unroll
        for (int ww = 0; ww < 8; ++ww) {
            z0 += partial[ww][pq];
            z1 += partial[ww][pq + 1];
        }
        float s0 = sigmoid_fast(z0);
        float s1 = sigmoid_fast(z1);

        short8v v0, v1;
        {
            int i0 = pq * 256 + ((cg ^ (pq & 7)) << 3);
            int i1 = (pq + 1) * 256 + ((cg ^ ((pq + 1) & 7)) << 3);
            v0 = *reinterpret_cast<const short8v*>(&Xl[i0]);
            v1 = *reinterpret_cast<const short8v*>(&Xl[i1]);
        }
#pragma unroll
        for (int j = 0; j < 8; ++j) {
            f32x2 o2;
            o2[0] = bf2f((unsigned short)v0[j]) * s0;
            o2[1] = bf2f((unsigned short)v1[j]) * s1;
            __builtin_nontemporal_store(o2, reinterpret_cast<f32x2*>(
                out + (size_t)(b * CCH + c0 + j) * SS + sb + pq));
        }
    }
}

// ---------------------------------------------------------------------------
// Kernel 3: exact fp32 fixup for keypoint pixels (<=152). One block per (b,k).
// Runs stream-ordered after main (nt stores are drained at main's endpgm).
// ---------------------------------------------------------------------------
__global__ __launch_bounds__(256) void fixup_kernel(
    const float* __restrict__ img,
    const float* __restrict__ img_fc_w,
    const float* __restrict__ aw,
    const float* __restrict__ attn_b,
    const float* __restrict__ cb,
    const float* __restrict__ delta,
    const int* __restrict__ pix,
    float* __restrict__ out)
{
    int bk = blockIdx.x;            // 0..151
    int b = bk / NK;
    int p = pix[bk];
    if (p < 0) return;              // uniform branch, before any barrier
    __shared__ float x[256];
    __shared__ float red[256];
    __shared__ float ssc;
    int t = threadIdx.x;
    const float* imgb = img + (size_t)b * CCH * SS;
    x[t] = imgb[(size_t)t * SS + p];
    __syncthreads();
    float dsum = 0.f;
    for (int k2 = 0; k2 < NK; ++k2)
        if (pix[b * NK + k2] == p) dsum += delta[t * NK + k2];
    float acc = cb[t] + dsum;
    for (int c = 0; c < CCH; ++c) acc += img_fc_w[t * CCH + c] * x[c];
    red[t] = aw[t] * tanh_fast(acc);
    __syncthreads();
    for (int off = 128; off > 0; off >>= 1) {
        if (t < off) red[t] += red[t + off];
        __syncthreads();
    }
    if (t == 0) ssc = sigmoid_fast(red[0] + attn_b[0]);
    __syncthreads();
    __builtin_nontemporal_store(x[t] * ssc, out + (size_t)(b * CCH + t) * SS + p);
}

// ---------------------------------------------------------------------------
extern "C" void kernel_launch(void* const* d_in, const int* in_sizes, int n_in,
                              void* d_out, int out_size, void* d_ws, size_t ws_size,
                              hipStream_t stream) {
    (void)in_sizes; (void)n_in; (void)out_size; (void)ws_size;
    const float* img       = (const float*)d_in[0];
    const float* kf        = (const float*)d_in[1];
    const float* img_fc_w  = (const float*)d_in[2];
    const float* img_fc_b  = (const float*)d_in[3];
    const float* kp_proj_w = (const float*)d_in[4];
    const float* kp_proj_b = (const float*)d_in[5];
    const float* kp_fc_w   = (const float*)d_in[6];
    const float* kp_fc_b   = (const float*)d_in[7];
    const float* attn_fc_w = (const float*)d_in[8];
    const float* attn_fc_b = (const float*)d_in[9];
    float* out = (float*)d_out;

    char* ws = (char*)d_ws;
    float* cb             = (float*)(ws);            // 256 f  ->   1024 B
    float* delta          = (float*)(ws + 1024);     // 4864 f -> 19456 B
    int*   pix            = (int*)  (ws + 20480);    // 152 i  ->   608 B
    unsigned short* Wfrag = (unsigned short*)(ws + 21504); // 131072 B

    precompute_kernel<<<1, 256, 0, stream>>>(kf, img_fc_w, img_fc_b, kp_proj_w,
                                             kp_proj_b, kp_fc_w, kp_fc_b,
                                             cb, delta, pix, Wfrag);
    main_kernel<<<NTIL, 512, 0, stream>>>(img, Wfrag, cb,
                                          attn_fc_w, attn_fc_b, out);
    fixup_kernel<<<NB * NK, 256, 0, stream>>>(img, img_fc_w, attn_fc_w, attn_fc_b,
                                              cb, delta, pix, out);
}